// Round 1
// baseline (4776.431 us; speedup 1.0000x reference)
//
#include <hip/hip_runtime.h>

#define N_NODES 100000
#define N_EDGES 1600000
#define N_GRAPHS 512
#define HDIM 128
#define OUTDIM 64

// ---------------- degree ----------------
__global__ __launch_bounds__(256) void k_deg(const int* __restrict__ dst, float* __restrict__ deg) {
    int i = blockIdx.x * blockDim.x + threadIdx.x;
    int stride = gridDim.x * blockDim.x;
    for (; i < N_EDGES; i += stride) atomicAdd(&deg[dst[i]], 1.0f);
}

__global__ __launch_bounds__(256) void k_dinv(float* __restrict__ deg) {
    int i = blockIdx.x * blockDim.x + threadIdx.x;
    int stride = gridDim.x * blockDim.x;
    for (; i < N_NODES; i += stride) deg[i] = rsqrtf(deg[i] + 1.0f);
}

// ---------------- GEMM: H = X @ W  (X:[N,128], W:[128,128]) ----------------
__global__ __launch_bounds__(256) void k_gemm(const float* __restrict__ X,
                                              const float* __restrict__ W,
                                              float* __restrict__ Hout) {
    __shared__ float Ws[HDIM * HDIM];  // 64 KB
    for (int t = threadIdx.x; t < HDIM * HDIM / 4; t += 256) {
        reinterpret_cast<float4*>(Ws)[t] = reinterpret_cast<const float4*>(W)[t];
    }
    __syncthreads();
    const int lane = threadIdx.x & 63;
    int wid = (blockIdx.x * blockDim.x + threadIdx.x) >> 6;
    const int nw = (gridDim.x * blockDim.x) >> 6;
    for (int r = wid; r < N_NODES; r += nw) {
        float2 xr = reinterpret_cast<const float2*>(X + (size_t)r * HDIM)[lane];
        float acc0 = 0.f, acc1 = 0.f;
#pragma unroll 16
        for (int k2 = 0; k2 < 64; ++k2) {
            float xa = __shfl(xr.x, k2);
            float xb = __shfl(xr.y, k2);
            acc0 += xa * Ws[(2 * k2) * HDIM + lane];
            acc0 += xb * Ws[(2 * k2 + 1) * HDIM + lane];
            acc1 += xa * Ws[(2 * k2) * HDIM + 64 + lane];
            acc1 += xb * Ws[(2 * k2 + 1) * HDIM + 64 + lane];
        }
        Hout[(size_t)r * HDIM + lane] = acc0;
        Hout[(size_t)r * HDIM + 64 + lane] = acc1;
    }
}

// ---------------- edge scatter: agg[dst] += h[src]*dinv[src]*dinv[dst] ----------------
__global__ __launch_bounds__(256) void k_scatter(const float* __restrict__ Hm,
                                                 const int* __restrict__ src,
                                                 const int* __restrict__ dst,
                                                 const float* __restrict__ dinv,
                                                 float* __restrict__ agg) {
    const int lane = threadIdx.x & 63;
    int wid = (blockIdx.x * blockDim.x + threadIdx.x) >> 6;
    const int nw = (gridDim.x * blockDim.x) >> 6;
    for (int e = wid; e < N_EDGES; e += nw) {
        int s = src[e], d = dst[e];
        float coef = dinv[s] * dinv[d];
        float2 hv = reinterpret_cast<const float2*>(Hm + (size_t)s * HDIM)[lane];
        float* ap = agg + (size_t)d * HDIM + lane * 2;
        atomicAdd(ap, hv.x * coef);
        atomicAdd(ap + 1, hv.y * coef);
    }
}

// ---------------- epilogue: self term + bias + layernorm + relu ----------------
__global__ __launch_bounds__(256) void k_epi(const float* __restrict__ agg,
                                             const float* __restrict__ Hm,
                                             const float* __restrict__ dinv,
                                             const float* __restrict__ b,
                                             const float* __restrict__ g,
                                             const float* __restrict__ be,
                                             float* __restrict__ outp) {
    const int lane = threadIdx.x & 63;
    int wid = (blockIdx.x * blockDim.x + threadIdx.x) >> 6;
    const int nw = (gridDim.x * blockDim.x) >> 6;
    float2 bb = reinterpret_cast<const float2*>(b)[lane];
    float2 gg = reinterpret_cast<const float2*>(g)[lane];
    float2 bee = reinterpret_cast<const float2*>(be)[lane];
    for (int i = wid; i < N_NODES; i += nw) {
        float di = dinv[i];
        float d2 = di * di;
        float2 a = reinterpret_cast<const float2*>(agg + (size_t)i * HDIM)[lane];
        float2 h = reinterpret_cast<const float2*>(Hm + (size_t)i * HDIM)[lane];
        float vx = a.x + h.x * d2 + bb.x;
        float vy = a.y + h.y * d2 + bb.y;
        float s = vx + vy, sq = vx * vx + vy * vy;
#pragma unroll
        for (int o = 1; o < 64; o <<= 1) {
            s += __shfl_xor(s, o);
            sq += __shfl_xor(sq, o);
        }
        float m = s * (1.0f / HDIM);
        float var = sq * (1.0f / HDIM) - m * m;
        float rs = rsqrtf(var + 1e-5f);
        float ox = fmaxf((vx - m) * rs * gg.x + bee.x, 0.f);
        float oy = fmaxf((vy - m) * rs * gg.y + bee.y, 0.f);
        reinterpret_cast<float2*>(outp + (size_t)i * HDIM)[lane] = make_float2(ox, oy);
    }
}

// ---------------- pool: pooled[batch[i]] += A[i]  (batch sorted -> chunked) ----------------
__global__ __launch_bounds__(256) void k_pool(const float* __restrict__ A,
                                              const int* __restrict__ batch,
                                              float* __restrict__ pooled) {
    const int CH = 16;
    const int lane = threadIdx.x & 63;
    int wid = (blockIdx.x * blockDim.x + threadIdx.x) >> 6;
    const int nw = (gridDim.x * blockDim.x) >> 6;
    const int nchunks = (N_NODES + CH - 1) / CH;
    for (int c = wid; c < nchunks; c += nw) {
        int i0 = c * CH;
        int i1 = min(i0 + CH, N_NODES);
        float ax = 0.f, ay = 0.f;
        int curb = batch[i0];
        for (int i = i0; i < i1; ++i) {
            int bg = batch[i];
            if (bg != curb) {
                float* p = pooled + (size_t)curb * HDIM + lane * 2;
                atomicAdd(p, ax);
                atomicAdd(p + 1, ay);
                ax = 0.f; ay = 0.f;
                curb = bg;
            }
            float2 v = reinterpret_cast<const float2*>(A + (size_t)i * HDIM)[lane];
            ax += v.x;
            ay += v.y;
        }
        float* p = pooled + (size_t)curb * HDIM + lane * 2;
        atomicAdd(p, ax);
        atomicAdd(p + 1, ay);
    }
}

// ---------------- head: out = pooled @ Wf + bf ----------------
__global__ __launch_bounds__(256) void k_head(const float* __restrict__ pooled,
                                              const float* __restrict__ Wf,
                                              const float* __restrict__ bf,
                                              float* __restrict__ out) {
    int idx = blockIdx.x * blockDim.x + threadIdx.x;
    if (idx >= N_GRAPHS * OUTDIM) return;
    int gI = idx / OUTDIM;
    int o = idx % OUTDIM;
    float acc = bf[o];
    const float* pr = pooled + (size_t)gI * HDIM;
#pragma unroll 8
    for (int k = 0; k < HDIM; ++k) acc += pr[k] * Wf[k * OUTDIM + o];
    out[idx] = acc;
}

extern "C" void kernel_launch(void* const* d_in, const int* in_sizes, int n_in,
                              void* d_out, int out_size, void* d_ws, size_t ws_size,
                              hipStream_t stream) {
    const float* x = (const float*)d_in[0];
    const int* ei = (const int*)d_in[1];
    const int* src = ei;
    const int* dst = ei + N_EDGES;
    const int* batch = (const int*)d_in[2];
    const float* W[3] = {(const float*)d_in[3], (const float*)d_in[7], (const float*)d_in[11]};
    const float* bb[3] = {(const float*)d_in[4], (const float*)d_in[8], (const float*)d_in[12]};
    const float* gg[3] = {(const float*)d_in[5], (const float*)d_in[9], (const float*)d_in[13]};
    const float* be[3] = {(const float*)d_in[6], (const float*)d_in[10], (const float*)d_in[14]};
    const float* Wf = (const float*)d_in[15];
    const float* bf = (const float*)d_in[16];
    float* out = (float*)d_out;

    float* ws = (float*)d_ws;
    float* dinv = ws;                              // N_NODES
    float* A = dinv + N_NODES;                     // N*128  (layer io)
    float* C = A + (size_t)N_NODES * HDIM;         // N*128  (h = x@W)
    float* B = C + (size_t)N_NODES * HDIM;         // N*128  (agg)
    float* pooled = B + (size_t)N_NODES * HDIM;    // 512*128

    // degree -> dinv
    hipMemsetAsync(dinv, 0, N_NODES * sizeof(float), stream);
    k_deg<<<2048, 256, 0, stream>>>(dst, dinv);
    k_dinv<<<(N_NODES + 255) / 256, 256, 0, stream>>>(dinv);

    const float* cur = x;
    for (int l = 0; l < 3; ++l) {
        k_gemm<<<512, 256, 0, stream>>>(cur, W[l], C);
        hipMemsetAsync(B, 0, (size_t)N_NODES * HDIM * sizeof(float), stream);
        k_scatter<<<16384, 256, 0, stream>>>(C, src, dst, dinv, B);
        k_epi<<<4096, 256, 0, stream>>>(B, C, dinv, bb[l], gg[l], be[l], A);
        cur = A;
    }

    hipMemsetAsync(pooled, 0, N_GRAPHS * HDIM * sizeof(float), stream);
    k_pool<<<((N_NODES + 15) / 16 + 3) / 4, 256, 0, stream>>>(A, batch, pooled);
    k_head<<<(N_GRAPHS * OUTDIM + 255) / 256, 256, 0, stream>>>(pooled, Wf, bf, out);
}

// Round 2
// 907.041 us; speedup vs baseline: 5.2659x; 5.2659x over previous
//
#include <hip/hip_runtime.h>

#define N_NODES 100000
#define N_EDGES 1600000
#define N_GRAPHS 512
#define HDIM 128
#define OUTDIM 64
#define NB_SCAN 391  // ceil(100000/256)

// ---------------- degree histogram (int) ----------------
__global__ __launch_bounds__(256) void k_count(const int* __restrict__ dst, int* __restrict__ cnt) {
    int i = blockIdx.x * blockDim.x + threadIdx.x;
    int stride = gridDim.x * blockDim.x;
    for (; i < N_EDGES; i += stride) atomicAdd(&cnt[dst[i]], 1);
}

__global__ __launch_bounds__(256) void k_dinv(const int* __restrict__ cnt, float* __restrict__ dinv) {
    int i = blockIdx.x * blockDim.x + threadIdx.x;
    int stride = gridDim.x * blockDim.x;
    for (; i < N_NODES; i += stride) dinv[i] = rsqrtf((float)cnt[i] + 1.0f);
}

// ---------------- exclusive scan (3 kernels) ----------------
__global__ __launch_bounds__(256) void k_scan1(const int* __restrict__ cnt,
                                               int* __restrict__ rowptr,
                                               int* __restrict__ bsum) {
    int i = blockIdx.x * 256 + threadIdx.x;
    int v = (i < N_NODES) ? cnt[i] : 0;
    int lane = threadIdx.x & 63;
    int wav = threadIdx.x >> 6;
    int incl = v;
#pragma unroll
    for (int o = 1; o < 64; o <<= 1) {
        int t = __shfl_up(incl, o);
        if (lane >= o) incl += t;
    }
    __shared__ int wsum[4];
    if (lane == 63) wsum[wav] = incl;
    __syncthreads();
    int woff = 0;
    for (int w = 0; w < wav; ++w) woff += wsum[w];
    int excl = incl - v + woff;
    if (i < N_NODES) rowptr[i] = excl;
    if (threadIdx.x == 255) bsum[blockIdx.x] = excl + v;
}

__global__ __launch_bounds__(512) void k_scan2(int* __restrict__ bsum) {
    int i = threadIdx.x;
    int v = (i < NB_SCAN) ? bsum[i] : 0;
    int lane = threadIdx.x & 63;
    int wav = threadIdx.x >> 6;
    int incl = v;
#pragma unroll
    for (int o = 1; o < 64; o <<= 1) {
        int t = __shfl_up(incl, o);
        if (lane >= o) incl += t;
    }
    __shared__ int wsum[8];
    if (lane == 63) wsum[wav] = incl;
    __syncthreads();
    int woff = 0;
    for (int w = 0; w < wav; ++w) woff += wsum[w];
    int excl = incl - v + woff;
    if (i < NB_SCAN) bsum[i] = excl;
}

__global__ __launch_bounds__(256) void k_scan3(int* __restrict__ rowptr, const int* __restrict__ bsum) {
    int i = blockIdx.x * 256 + threadIdx.x;
    if (i < N_NODES) rowptr[i] += bsum[i >> 8];
    if (i == 0) rowptr[N_NODES] = N_EDGES;
}

// ---------------- CSR fill: esrc sorted by dst ----------------
__global__ __launch_bounds__(256) void k_fill(const int* __restrict__ src,
                                              const int* __restrict__ dst,
                                              const int* __restrict__ rowptr,
                                              int* __restrict__ cursor,
                                              int* __restrict__ esrc) {
    int e = blockIdx.x * blockDim.x + threadIdx.x;
    int stride = gridDim.x * blockDim.x;
    for (; e < N_EDGES; e += stride) {
        int d = dst[e];
        int p = atomicAdd(&cursor[d], 1);
        esrc[rowptr[d] + p] = src[e];
    }
}

// ---------------- tiled GEMM: H = X @ W  (tile 64 rows x 128 cols) ----------------
#define TM 64
__global__ __launch_bounds__(256) void k_gemm(const float* __restrict__ X,
                                              const float* __restrict__ W,
                                              float* __restrict__ Hout) {
    __shared__ __align__(16) float Ws[HDIM * HDIM];   // 64 KB
    __shared__ __align__(16) float Xs[TM][132];       // ~33.8 KB (pad 132 for banks)
    const int t = threadIdx.x;
    const int row0 = blockIdx.x * TM;
    for (int u = t; u < HDIM * HDIM / 4; u += 256)
        reinterpret_cast<float4*>(Ws)[u] = reinterpret_cast<const float4*>(W)[u];
    for (int u = t; u < TM * 32; u += 256) {
        int r = u >> 5;
        int c4 = u & 31;
        float4 v = make_float4(0.f, 0.f, 0.f, 0.f);
        if (row0 + r < N_NODES)
            v = reinterpret_cast<const float4*>(X + (size_t)(row0 + r) * HDIM)[c4];
        *reinterpret_cast<float4*>(&Xs[r][c4 * 4]) = v;
    }
    __syncthreads();

    const int trg = t >> 5;          // 0..7 -> rows trg*8 .. trg*8+7
    const int tc = (t & 31) * 4;     // cols tc..tc+3
    float acc[8][4];
#pragma unroll
    for (int r = 0; r < 8; ++r)
#pragma unroll
        for (int c = 0; c < 4; ++c) acc[r][c] = 0.f;

#pragma unroll 2
    for (int k = 0; k < HDIM; ++k) {
        float4 wv = *reinterpret_cast<const float4*>(&Ws[k * HDIM + tc]);
        float xv[8];
#pragma unroll
        for (int r = 0; r < 8; ++r) xv[r] = Xs[trg * 8 + r][k];
#pragma unroll
        for (int r = 0; r < 8; ++r) {
            acc[r][0] += xv[r] * wv.x;
            acc[r][1] += xv[r] * wv.y;
            acc[r][2] += xv[r] * wv.z;
            acc[r][3] += xv[r] * wv.w;
        }
    }
#pragma unroll
    for (int r = 0; r < 8; ++r) {
        int row = row0 + trg * 8 + r;
        if (row < N_NODES) {
            float4 o = make_float4(acc[r][0], acc[r][1], acc[r][2], acc[r][3]);
            *reinterpret_cast<float4*>(Hout + (size_t)row * HDIM + tc) = o;
        }
    }
}

// ---------------- gather + self-loop + bias + layernorm + relu ----------------
__global__ __launch_bounds__(256) void k_gather(const float* __restrict__ Hm,
                                                const int* __restrict__ rowptr,
                                                const int* __restrict__ esrc,
                                                const float* __restrict__ dinv,
                                                const float* __restrict__ b,
                                                const float* __restrict__ g,
                                                const float* __restrict__ be,
                                                float* __restrict__ outp) {
    const int lane = threadIdx.x & 63;
    int wid = (blockIdx.x * blockDim.x + threadIdx.x) >> 6;
    const int nw = (gridDim.x * blockDim.x) >> 6;
    float2 bb = reinterpret_cast<const float2*>(b)[lane];
    float2 gg = reinterpret_cast<const float2*>(g)[lane];
    float2 bee = reinterpret_cast<const float2*>(be)[lane];
    for (int i = wid; i < N_NODES; i += nw) {
        int row0 = rowptr[i], row1 = rowptr[i + 1];
        float accx = 0.f, accy = 0.f;
        int j = row0;
        for (; j + 1 < row1; j += 2) {
            int s0 = esrc[j], s1 = esrc[j + 1];
            float d0 = dinv[s0], d1 = dinv[s1];
            float2 h0 = reinterpret_cast<const float2*>(Hm + (size_t)s0 * HDIM)[lane];
            float2 h1 = reinterpret_cast<const float2*>(Hm + (size_t)s1 * HDIM)[lane];
            accx += d0 * h0.x + d1 * h1.x;
            accy += d0 * h0.y + d1 * h1.y;
        }
        if (j < row1) {
            int s0 = esrc[j];
            float d0 = dinv[s0];
            float2 h0 = reinterpret_cast<const float2*>(Hm + (size_t)s0 * HDIM)[lane];
            accx += d0 * h0.x;
            accy += d0 * h0.y;
        }
        float di = dinv[i];
        float2 hs = reinterpret_cast<const float2*>(Hm + (size_t)i * HDIM)[lane];
        float vx = accx * di + hs.x * di * di + bb.x;
        float vy = accy * di + hs.y * di * di + bb.y;
        // layernorm over 128 elems (2 per lane)
        float s = vx + vy, sq = vx * vx + vy * vy;
#pragma unroll
        for (int o = 1; o < 64; o <<= 1) {
            s += __shfl_xor(s, o);
            sq += __shfl_xor(sq, o);
        }
        float m = s * (1.0f / HDIM);
        float var = sq * (1.0f / HDIM) - m * m;
        float rs = rsqrtf(var + 1e-5f);
        float ox = fmaxf((vx - m) * rs * gg.x + bee.x, 0.f);
        float oy = fmaxf((vy - m) * rs * gg.y + bee.y, 0.f);
        reinterpret_cast<float2*>(outp + (size_t)i * HDIM)[lane] = make_float2(ox, oy);
    }
}

// ---------------- pool: pooled[batch[i]] += A[i]  (batch sorted -> chunked) ----------------
__global__ __launch_bounds__(256) void k_pool(const float* __restrict__ A,
                                              const int* __restrict__ batch,
                                              float* __restrict__ pooled) {
    const int CH = 16;
    const int lane = threadIdx.x & 63;
    int wid = (blockIdx.x * blockDim.x + threadIdx.x) >> 6;
    const int nw = (gridDim.x * blockDim.x) >> 6;
    const int nchunks = (N_NODES + CH - 1) / CH;
    for (int c = wid; c < nchunks; c += nw) {
        int i0 = c * CH;
        int i1 = min(i0 + CH, N_NODES);
        float ax = 0.f, ay = 0.f;
        int curb = batch[i0];
        for (int i = i0; i < i1; ++i) {
            int bg = batch[i];
            if (bg != curb) {
                float* p = pooled + (size_t)curb * HDIM + lane * 2;
                atomicAdd(p, ax);
                atomicAdd(p + 1, ay);
                ax = 0.f; ay = 0.f;
                curb = bg;
            }
            float2 v = reinterpret_cast<const float2*>(A + (size_t)i * HDIM)[lane];
            ax += v.x;
            ay += v.y;
        }
        float* p = pooled + (size_t)curb * HDIM + lane * 2;
        atomicAdd(p, ax);
        atomicAdd(p + 1, ay);
    }
}

// ---------------- head: out = pooled @ Wf + bf ----------------
__global__ __launch_bounds__(256) void k_head(const float* __restrict__ pooled,
                                              const float* __restrict__ Wf,
                                              const float* __restrict__ bf,
                                              float* __restrict__ out) {
    int idx = blockIdx.x * blockDim.x + threadIdx.x;
    if (idx >= N_GRAPHS * OUTDIM) return;
    int gI = idx / OUTDIM;
    int o = idx % OUTDIM;
    float acc = bf[o];
    const float* pr = pooled + (size_t)gI * HDIM;
#pragma unroll 8
    for (int k = 0; k < HDIM; ++k) acc += pr[k] * Wf[k * OUTDIM + o];
    out[idx] = acc;
}

extern "C" void kernel_launch(void* const* d_in, const int* in_sizes, int n_in,
                              void* d_out, int out_size, void* d_ws, size_t ws_size,
                              hipStream_t stream) {
    const float* x = (const float*)d_in[0];
    const int* ei = (const int*)d_in[1];
    const int* src = ei;
    const int* dst = ei + N_EDGES;
    const int* batch = (const int*)d_in[2];
    const float* W[3] = {(const float*)d_in[3], (const float*)d_in[7], (const float*)d_in[11]};
    const float* bb[3] = {(const float*)d_in[4], (const float*)d_in[8], (const float*)d_in[12]};
    const float* gg[3] = {(const float*)d_in[5], (const float*)d_in[9], (const float*)d_in[13]};
    const float* be[3] = {(const float*)d_in[6], (const float*)d_in[10], (const float*)d_in[14]};
    const float* Wf = (const float*)d_in[15];
    const float* bf = (const float*)d_in[16];
    float* out = (float*)d_out;

    float* fws = (float*)d_ws;
    float* dinv = fws;                                     // N
    float* A = dinv + N_NODES;                             // N*128
    float* C = A + (size_t)N_NODES * HDIM;                 // N*128
    float* pooled = C + (size_t)N_NODES * HDIM;            // G*128
    int* cnt = (int*)(pooled + (size_t)N_GRAPHS * HDIM);   // N
    int* rowptr = cnt + N_NODES;                           // N+1
    int* cursor = rowptr + N_NODES + 1;                    // N
    int* bsum = cursor + N_NODES;                          // 512
    int* esrc = bsum + 512;                                // E

    // degree histogram -> dinv ; CSR build
    hipMemsetAsync(cnt, 0, N_NODES * sizeof(int), stream);
    hipMemsetAsync(cursor, 0, N_NODES * sizeof(int), stream);
    k_count<<<2048, 256, 0, stream>>>(dst, cnt);
    k_dinv<<<(N_NODES + 255) / 256, 256, 0, stream>>>(cnt, dinv);
    k_scan1<<<NB_SCAN, 256, 0, stream>>>(cnt, rowptr, bsum);
    k_scan2<<<1, 512, 0, stream>>>(bsum);
    k_scan3<<<NB_SCAN, 256, 0, stream>>>(rowptr, bsum);
    k_fill<<<2048, 256, 0, stream>>>(src, dst, rowptr, cursor, esrc);

    const int gemm_blocks = (N_NODES + TM - 1) / TM;
    const float* cur = x;
    for (int l = 0; l < 3; ++l) {
        k_gemm<<<gemm_blocks, 256, 0, stream>>>(cur, W[l], C);
        k_gather<<<25000, 256, 0, stream>>>(C, rowptr, esrc, dinv, bb[l], gg[l], be[l], A);
        cur = A;
    }

    hipMemsetAsync(pooled, 0, N_GRAPHS * HDIM * sizeof(float), stream);
    k_pool<<<((N_NODES + 15) / 16 + 3) / 4, 256, 0, stream>>>(A, batch, pooled);
    k_head<<<(N_GRAPHS * OUTDIM + 255) / 256, 256, 0, stream>>>(pooled, Wf, bf, out);
}

// Round 3
// 620.692 us; speedup vs baseline: 7.6953x; 1.4613x over previous
//
#include <hip/hip_runtime.h>

#define N_NODES 100000
#define N_EDGES 1600000
#define N_GRAPHS 512
#define HDIM 128
#define HP 64        // packed u32 per row (2 bf16 each)
#define OUTDIM 64
#define NB_SCAN 391  // ceil(100000/256)

__device__ __forceinline__ float bflo(unsigned u) { return __uint_as_float(u << 16); }
__device__ __forceinline__ float bfhi(unsigned u) { return __uint_as_float(u & 0xffff0000u); }
__device__ __forceinline__ unsigned bf16r(float f) {
    unsigned u = __float_as_uint(f);
    return (u + 0x7fffu + ((u >> 16) & 1u)) >> 16;
}
__device__ __forceinline__ unsigned packbf(float a, float b) {
    return bf16r(a) | (bf16r(b) << 16);
}

// ---------------- degree histogram (int) ----------------
__global__ __launch_bounds__(256) void k_count(const int* __restrict__ dst, int* __restrict__ cnt) {
    int i = blockIdx.x * blockDim.x + threadIdx.x;
    int stride = gridDim.x * blockDim.x;
    for (; i < N_EDGES; i += stride) atomicAdd(&cnt[dst[i]], 1);
}

__global__ __launch_bounds__(256) void k_dinv(const int* __restrict__ cnt, float* __restrict__ dinv) {
    int i = blockIdx.x * blockDim.x + threadIdx.x;
    int stride = gridDim.x * blockDim.x;
    for (; i < N_NODES; i += stride) dinv[i] = rsqrtf((float)cnt[i] + 1.0f);
}

// ---------------- exclusive scan (3 kernels) ----------------
__global__ __launch_bounds__(256) void k_scan1(const int* __restrict__ cnt,
                                               int* __restrict__ rowptr,
                                               int* __restrict__ bsum) {
    int i = blockIdx.x * 256 + threadIdx.x;
    int v = (i < N_NODES) ? cnt[i] : 0;
    int lane = threadIdx.x & 63;
    int wav = threadIdx.x >> 6;
    int incl = v;
#pragma unroll
    for (int o = 1; o < 64; o <<= 1) {
        int t = __shfl_up(incl, o);
        if (lane >= o) incl += t;
    }
    __shared__ int wsum[4];
    if (lane == 63) wsum[wav] = incl;
    __syncthreads();
    int woff = 0;
    for (int w = 0; w < wav; ++w) woff += wsum[w];
    int excl = incl - v + woff;
    if (i < N_NODES) rowptr[i] = excl;
    if (threadIdx.x == 255) bsum[blockIdx.x] = excl + v;
}

__global__ __launch_bounds__(512) void k_scan2(int* __restrict__ bsum) {
    int i = threadIdx.x;
    int v = (i < NB_SCAN) ? bsum[i] : 0;
    int lane = threadIdx.x & 63;
    int wav = threadIdx.x >> 6;
    int incl = v;
#pragma unroll
    for (int o = 1; o < 64; o <<= 1) {
        int t = __shfl_up(incl, o);
        if (lane >= o) incl += t;
    }
    __shared__ int wsum[8];
    if (lane == 63) wsum[wav] = incl;
    __syncthreads();
    int woff = 0;
    for (int w = 0; w < wav; ++w) woff += wsum[w];
    int excl = incl - v + woff;
    if (i < NB_SCAN) bsum[i] = excl;
}

__global__ __launch_bounds__(256) void k_scan3(int* __restrict__ rowptr, const int* __restrict__ bsum) {
    int i = blockIdx.x * 256 + threadIdx.x;
    if (i < N_NODES) rowptr[i] += bsum[i >> 8];
    if (i == 0) rowptr[N_NODES] = N_EDGES;
}

// ---------------- CSR fill: esrc sorted by dst ----------------
__global__ __launch_bounds__(256) void k_fill(const int* __restrict__ src,
                                              const int* __restrict__ dst,
                                              const int* __restrict__ rowptr,
                                              int* __restrict__ cursor,
                                              int* __restrict__ esrc) {
    int e = blockIdx.x * blockDim.x + threadIdx.x;
    int stride = gridDim.x * blockDim.x;
    for (; e < N_EDGES; e += stride) {
        int d = dst[e];
        int p = atomicAdd(&cursor[d], 1);
        esrc[rowptr[d] + p] = src[e];
    }
}

// ---------------- convert fp32 x -> packed bf16 ----------------
__global__ __launch_bounds__(256) void k_cvt(const float* __restrict__ x, unsigned* __restrict__ xb) {
    int i = blockIdx.x * blockDim.x + threadIdx.x;
    int stride = gridDim.x * blockDim.x;
    const int n = N_NODES * HP;
    for (; i < n; i += stride) {
        float2 v = reinterpret_cast<const float2*>(x)[i];
        xb[i] = packbf(v.x, v.y);
    }
}

// ---------------- tiled GEMM: Cb = (Xb @ W) * dinv[row], bf16 in/out ----------------
#define TM 64
__global__ __launch_bounds__(256) void k_gemm(const unsigned* __restrict__ Xb,
                                              const float* __restrict__ W,
                                              const float* __restrict__ dinv,
                                              unsigned* __restrict__ Cb) {
    __shared__ __align__(16) unsigned Wb[HDIM * HP];  // bf16-packed W: 32 KB
    __shared__ __align__(16) float Xs[TM][132];       // 33.8 KB
    const int t = threadIdx.x;
    const int row0 = blockIdx.x * TM;
    // stage W (fp32 global -> bf16 LDS)
    for (int u = t; u < HDIM * HP; u += 256) {
        float2 w2 = reinterpret_cast<const float2*>(W)[u];
        Wb[u] = packbf(w2.x, w2.y);
    }
    // stage X tile (bf16 global -> fp32 LDS)
    for (int u = t; u < TM * 16; u += 256) {
        int r = u >> 4;
        int q = u & 15;  // 8 cols per q
        uint4 v = make_uint4(0, 0, 0, 0);
        if (row0 + r < N_NODES)
            v = reinterpret_cast<const uint4*>(Xb + (size_t)(row0 + r) * HP)[q];
        float* p = &Xs[r][q * 8];
        p[0] = bflo(v.x); p[1] = bfhi(v.x);
        p[2] = bflo(v.y); p[3] = bfhi(v.y);
        p[4] = bflo(v.z); p[5] = bfhi(v.z);
        p[6] = bflo(v.w); p[7] = bfhi(v.w);
    }
    __syncthreads();

    const int trg = t >> 5;       // 0..7 -> rows trg*8..+7
    const int tcp = (t & 31) * 2; // packed col-pair index (cols 4*(t&31)..+3)
    float acc[8][4];
#pragma unroll
    for (int r = 0; r < 8; ++r)
#pragma unroll
        for (int c = 0; c < 4; ++c) acc[r][c] = 0.f;

#pragma unroll 4
    for (int k = 0; k < HDIM; ++k) {
        uint2 w2 = *reinterpret_cast<const uint2*>(&Wb[k * HP + tcp]);
        float w0 = bflo(w2.x), w1 = bfhi(w2.x), w2f = bflo(w2.y), w3 = bfhi(w2.y);
        float xv[8];
#pragma unroll
        for (int r = 0; r < 8; ++r) xv[r] = Xs[trg * 8 + r][k];
#pragma unroll
        for (int r = 0; r < 8; ++r) {
            acc[r][0] += xv[r] * w0;
            acc[r][1] += xv[r] * w1;
            acc[r][2] += xv[r] * w2f;
            acc[r][3] += xv[r] * w3;
        }
    }
#pragma unroll
    for (int r = 0; r < 8; ++r) {
        int row = row0 + trg * 8 + r;
        if (row < N_NODES) {
            float d = dinv[row];
            uint2 o;
            o.x = packbf(acc[r][0] * d, acc[r][1] * d);
            o.y = packbf(acc[r][2] * d, acc[r][3] * d);
            *reinterpret_cast<uint2*>(Cb + (size_t)row * HP + tcp) = o;
        }
    }
}

// ---------------- gather + self + bias + layernorm + relu (bf16 rows) ----------------
__global__ __launch_bounds__(256) void k_gather(const unsigned* __restrict__ Cb,
                                                const int* __restrict__ rowptr,
                                                const int* __restrict__ esrc,
                                                const float* __restrict__ dinv,
                                                const float* __restrict__ b,
                                                const float* __restrict__ g,
                                                const float* __restrict__ be,
                                                unsigned* __restrict__ Ab) {
    const int lane = threadIdx.x & 63;
    int wid = (blockIdx.x * blockDim.x + threadIdx.x) >> 6;
    const int nw = (gridDim.x * blockDim.x) >> 6;
    float2 bb = reinterpret_cast<const float2*>(b)[lane];
    float2 gg = reinterpret_cast<const float2*>(g)[lane];
    float2 bee = reinterpret_cast<const float2*>(be)[lane];
    for (int i = wid; i < N_NODES; i += nw) {
        int r0 = rowptr[i], r1 = rowptr[i + 1];
        float ax = 0.f, ay = 0.f;
        int j = r0;
        for (; j + 3 < r1; j += 4) {
            int s0 = esrc[j], s1 = esrc[j + 1], s2 = esrc[j + 2], s3 = esrc[j + 3];
            unsigned u0 = Cb[(size_t)s0 * HP + lane];
            unsigned u1 = Cb[(size_t)s1 * HP + lane];
            unsigned u2 = Cb[(size_t)s2 * HP + lane];
            unsigned u3 = Cb[(size_t)s3 * HP + lane];
            ax += (bflo(u0) + bflo(u1)) + (bflo(u2) + bflo(u3));
            ay += (bfhi(u0) + bfhi(u1)) + (bfhi(u2) + bfhi(u3));
        }
        for (; j < r1; ++j) {
            unsigned u0 = Cb[(size_t)esrc[j] * HP + lane];
            ax += bflo(u0);
            ay += bfhi(u0);
        }
        unsigned us = Cb[(size_t)i * HP + lane];  // self-loop (already dinv-scaled)
        ax += bflo(us);
        ay += bfhi(us);
        float di = dinv[i];
        float vx = ax * di + bb.x;
        float vy = ay * di + bb.y;
        float s = vx + vy, sq = vx * vx + vy * vy;
#pragma unroll
        for (int o = 1; o < 64; o <<= 1) {
            s += __shfl_xor(s, o);
            sq += __shfl_xor(sq, o);
        }
        float m = s * (1.0f / HDIM);
        float var = sq * (1.0f / HDIM) - m * m;
        float rs = rsqrtf(var + 1e-5f);
        float ox = fmaxf((vx - m) * rs * gg.x + bee.x, 0.f);
        float oy = fmaxf((vy - m) * rs * gg.y + bee.y, 0.f);
        Ab[(size_t)i * HP + lane] = packbf(ox, oy);
    }
}

// ---------------- pool: pooled[batch[i]] += A[i] (bf16 rows, sorted batch) ----------------
__global__ __launch_bounds__(256) void k_pool(const unsigned* __restrict__ Ab,
                                              const int* __restrict__ batch,
                                              float* __restrict__ pooled) {
    const int CH = 16;
    const int lane = threadIdx.x & 63;
    int wid = (blockIdx.x * blockDim.x + threadIdx.x) >> 6;
    const int nw = (gridDim.x * blockDim.x) >> 6;
    const int nchunks = (N_NODES + CH - 1) / CH;
    for (int c = wid; c < nchunks; c += nw) {
        int i0 = c * CH;
        int i1 = min(i0 + CH, N_NODES);
        float ax = 0.f, ay = 0.f;
        int curb = batch[i0];
        for (int i = i0; i < i1; ++i) {
            int bg = batch[i];
            if (bg != curb) {
                float* p = pooled + (size_t)curb * HDIM + lane * 2;
                atomicAdd(p, ax);
                atomicAdd(p + 1, ay);
                ax = 0.f; ay = 0.f;
                curb = bg;
            }
            unsigned v = Ab[(size_t)i * HP + lane];
            ax += bflo(v);
            ay += bfhi(v);
        }
        float* p = pooled + (size_t)curb * HDIM + lane * 2;
        atomicAdd(p, ax);
        atomicAdd(p + 1, ay);
    }
}

// ---------------- head: out = pooled @ Wf + bf ----------------
__global__ __launch_bounds__(256) void k_head(const float* __restrict__ pooled,
                                              const float* __restrict__ Wf,
                                              const float* __restrict__ bf,
                                              float* __restrict__ out) {
    int idx = blockIdx.x * blockDim.x + threadIdx.x;
    if (idx >= N_GRAPHS * OUTDIM) return;
    int gI = idx / OUTDIM;
    int o = idx % OUTDIM;
    float acc = bf[o];
    const float* pr = pooled + (size_t)gI * HDIM;
#pragma unroll 8
    for (int k = 0; k < HDIM; ++k) acc += pr[k] * Wf[k * OUTDIM + o];
    out[idx] = acc;
}

extern "C" void kernel_launch(void* const* d_in, const int* in_sizes, int n_in,
                              void* d_out, int out_size, void* d_ws, size_t ws_size,
                              hipStream_t stream) {
    const float* x = (const float*)d_in[0];
    const int* ei = (const int*)d_in[1];
    const int* src = ei;
    const int* dst = ei + N_EDGES;
    const int* batch = (const int*)d_in[2];
    const float* W[3] = {(const float*)d_in[3], (const float*)d_in[7], (const float*)d_in[11]};
    const float* bb[3] = {(const float*)d_in[4], (const float*)d_in[8], (const float*)d_in[12]};
    const float* gg[3] = {(const float*)d_in[5], (const float*)d_in[9], (const float*)d_in[13]};
    const float* be[3] = {(const float*)d_in[6], (const float*)d_in[10], (const float*)d_in[14]};
    const float* Wf = (const float*)d_in[15];
    const float* bf = (const float*)d_in[16];
    float* out = (float*)d_out;

    char* ws = (char*)d_ws;
    float* dinv = (float*)ws;                         ws += sizeof(float) * (N_NODES + 32);
    unsigned* Xb = (unsigned*)ws;                     ws += sizeof(unsigned) * (size_t)N_NODES * HP;
    unsigned* Ab = (unsigned*)ws;                     ws += sizeof(unsigned) * (size_t)N_NODES * HP;
    unsigned* Cb = (unsigned*)ws;                     ws += sizeof(unsigned) * (size_t)N_NODES * HP;
    float* pooled = (float*)ws;                       ws += sizeof(float) * N_GRAPHS * HDIM;
    int* cnt = (int*)ws;                              ws += sizeof(int) * N_NODES;
    int* rowptr = (int*)ws;                           ws += sizeof(int) * (N_NODES + 1);
    int* cursor = (int*)ws;                           ws += sizeof(int) * N_NODES;
    int* bsum = (int*)ws;                             ws += sizeof(int) * 512;
    int* esrc = (int*)ws;                             ws += sizeof(int) * N_EDGES;

    hipMemsetAsync(cnt, 0, N_NODES * sizeof(int), stream);
    hipMemsetAsync(cursor, 0, N_NODES * sizeof(int), stream);
    k_count<<<2048, 256, 0, stream>>>(dst, cnt);
    k_dinv<<<NB_SCAN, 256, 0, stream>>>(cnt, dinv);
    k_scan1<<<NB_SCAN, 256, 0, stream>>>(cnt, rowptr, bsum);
    k_scan2<<<1, 512, 0, stream>>>(bsum);
    k_scan3<<<NB_SCAN, 256, 0, stream>>>(rowptr, bsum);
    k_fill<<<2048, 256, 0, stream>>>(src, dst, rowptr, cursor, esrc);
    k_cvt<<<4096, 256, 0, stream>>>(x, Xb);

    const int gemm_blocks = (N_NODES + TM - 1) / TM;
    const unsigned* cur = Xb;
    for (int l = 0; l < 3; ++l) {
        k_gemm<<<gemm_blocks, 256, 0, stream>>>(cur, W[l], dinv, Cb);
        k_gather<<<25000, 256, 0, stream>>>(Cb, rowptr, esrc, dinv, bb[l], gg[l], be[l], Ab);
        cur = Ab;
    }

    hipMemsetAsync(pooled, 0, N_GRAPHS * HDIM * sizeof(float), stream);
    k_pool<<<1563, 256, 0, stream>>>(Ab, batch, pooled);
    k_head<<<(N_GRAPHS * OUTDIM + 255) / 256, 256, 0, stream>>>(pooled, Wf, bf, out);
}

// Round 4
// 597.313 us; speedup vs baseline: 7.9965x; 1.0391x over previous
//
#include <hip/hip_runtime.h>

#define N_NODES 100000
#define N_EDGES 1600000
#define N_GRAPHS 512
#define HDIM 128
#define HP 64        // packed u32 per row (2 bf16 each)
#define OUTDIM 64
#define NBUCK 391    // buckets of 256 dst nodes
#define SLAB 6144    // max edges per bucket (mean 4092, sigma 64)
#define EPB 4096     // edges per k_bucket block

__device__ __forceinline__ float bflo(unsigned u) { return __uint_as_float(u << 16); }
__device__ __forceinline__ float bfhi(unsigned u) { return __uint_as_float(u & 0xffff0000u); }
__device__ __forceinline__ unsigned bf16r(float f) {
    unsigned u = __float_as_uint(f);
    return (u + 0x7fffu + ((u >> 16) & 1u)) >> 16;
}
__device__ __forceinline__ unsigned packbf(float a, float b) {
    return bf16r(a) | (bf16r(b) << 16);
}

// ---------------- phase A: bucket scatter with block-local reservation ----------------
__global__ __launch_bounds__(256) void k_bucket(const int* __restrict__ src,
                                                const int* __restrict__ dst,
                                                int* __restrict__ gcur,
                                                unsigned* __restrict__ ebuck) {
    __shared__ int hist[NBUCK];
    __shared__ int base[NBUCK];
    __shared__ int cur[NBUCK];
    const int t = threadIdx.x;
    const int e0 = blockIdx.x * EPB;
    for (int b = t; b < NBUCK; b += 256) hist[b] = 0;
    __syncthreads();
    for (int i = t; i < EPB; i += 256) {
        int e = e0 + i;
        if (e < N_EDGES) atomicAdd(&hist[dst[e] >> 8], 1);
    }
    __syncthreads();
    for (int b = t; b < NBUCK; b += 256) {
        base[b] = atomicAdd(&gcur[b], hist[b]);
        cur[b] = 0;
    }
    __syncthreads();
    for (int i = t; i < EPB; i += 256) {
        int e = e0 + i;
        if (e < N_EDGES) {
            int d = dst[e], s = src[e];
            int b = d >> 8;
            int p = base[b] + atomicAdd(&cur[b], 1);
            if (p < SLAB)
                ebuck[(size_t)b * SLAB + p] = ((unsigned)s << 8) | (unsigned)(d & 255);
        }
    }
}

// ---------------- phase B: per-bucket exact sort + rbase/rend/dinv ----------------
__global__ __launch_bounds__(256) void k_bsort(const int* __restrict__ gcur,
                                               const unsigned* __restrict__ ebuck,
                                               int* __restrict__ esrc,
                                               int* __restrict__ rbase,
                                               int* __restrict__ rend,
                                               float* __restrict__ dinv) {
    __shared__ unsigned stage[SLAB];   // 24 KB
    __shared__ int hist[256], offs[256], cur[256];
    __shared__ int wsum[4];
    const int t = threadIdx.x;
    const int b = blockIdx.x;
    const int cnt = min(gcur[b], SLAB);
    hist[t] = 0;
    cur[t] = 0;
    __syncthreads();
    for (int i = t; i < cnt; i += 256) {
        unsigned u = ebuck[(size_t)b * SLAB + i];
        stage[i] = u;
        atomicAdd(&hist[u & 255], 1);
    }
    __syncthreads();
    // exclusive scan of hist[256]
    int v = hist[t];
    int lane = t & 63, wv = t >> 6;
    int incl = v;
#pragma unroll
    for (int o = 1; o < 64; o <<= 1) {
        int tmp = __shfl_up(incl, o);
        if (lane >= o) incl += tmp;
    }
    if (lane == 63) wsum[wv] = incl;
    __syncthreads();
    int woff = 0;
    for (int w = 0; w < wv; ++w) woff += wsum[w];
    int ex = incl - v + woff;
    offs[t] = ex;
    int d = b * 256 + t;
    if (d < N_NODES) {
        rbase[d] = b * SLAB + ex;
        rend[d] = b * SLAB + ex + v;
        dinv[d] = rsqrtf((float)v + 1.0f);
    }
    __syncthreads();
    for (int i = t; i < cnt; i += 256) {
        unsigned u = stage[i];
        int dl = u & 255;
        int p = atomicAdd(&cur[dl], 1);
        esrc[b * SLAB + offs[dl] + p] = (int)(u >> 8);
    }
}

// ---------------- tiled GEMM: Cb = (X @ W) * dinv[row], bf16 out ----------------
#define TM 64
__global__ __launch_bounds__(256) void k_gemm(const unsigned* __restrict__ Xb,
                                              const float* __restrict__ Xf,
                                              const float* __restrict__ W,
                                              const float* __restrict__ dinv,
                                              unsigned* __restrict__ Cb) {
    __shared__ __align__(16) unsigned Wb[HDIM * HP];  // 32 KB
    __shared__ __align__(16) float Xs[TM][132];       // 33.8 KB
    const int t = threadIdx.x;
    const int row0 = blockIdx.x * TM;
    for (int u = t; u < HDIM * HP; u += 256) {
        float2 w2 = reinterpret_cast<const float2*>(W)[u];
        Wb[u] = packbf(w2.x, w2.y);
    }
    if (Xf) {
        // layer 0: stage fp32 x directly
        for (int u = t; u < TM * 32; u += 256) {
            int r = u >> 5, c4 = u & 31;
            float4 v = make_float4(0.f, 0.f, 0.f, 0.f);
            if (row0 + r < N_NODES)
                v = reinterpret_cast<const float4*>(Xf + (size_t)(row0 + r) * HDIM)[c4];
            *reinterpret_cast<float4*>(&Xs[r][c4 * 4]) = v;
        }
    } else {
        for (int u = t; u < TM * 16; u += 256) {
            int r = u >> 4, q = u & 15;
            uint4 v = make_uint4(0, 0, 0, 0);
            if (row0 + r < N_NODES)
                v = reinterpret_cast<const uint4*>(Xb + (size_t)(row0 + r) * HP)[q];
            float* p = &Xs[r][q * 8];
            p[0] = bflo(v.x); p[1] = bfhi(v.x);
            p[2] = bflo(v.y); p[3] = bfhi(v.y);
            p[4] = bflo(v.z); p[5] = bfhi(v.z);
            p[6] = bflo(v.w); p[7] = bfhi(v.w);
        }
    }
    __syncthreads();

    const int trg = t >> 5;
    const int tcp = (t & 31) * 2;
    float acc[8][4];
#pragma unroll
    for (int r = 0; r < 8; ++r)
#pragma unroll
        for (int c = 0; c < 4; ++c) acc[r][c] = 0.f;

#pragma unroll 4
    for (int k = 0; k < HDIM; ++k) {
        uint2 w2 = *reinterpret_cast<const uint2*>(&Wb[k * HP + tcp]);
        float w0 = bflo(w2.x), w1 = bfhi(w2.x), w2f = bflo(w2.y), w3 = bfhi(w2.y);
        float xv[8];
#pragma unroll
        for (int r = 0; r < 8; ++r) xv[r] = Xs[trg * 8 + r][k];
#pragma unroll
        for (int r = 0; r < 8; ++r) {
            acc[r][0] += xv[r] * w0;
            acc[r][1] += xv[r] * w1;
            acc[r][2] += xv[r] * w2f;
            acc[r][3] += xv[r] * w3;
        }
    }
#pragma unroll
    for (int r = 0; r < 8; ++r) {
        int row = row0 + trg * 8 + r;
        if (row < N_NODES) {
            float dv = dinv[row];
            uint2 o;
            o.x = packbf(acc[r][0] * dv, acc[r][1] * dv);
            o.y = packbf(acc[r][2] * dv, acc[r][3] * dv);
            *reinterpret_cast<uint2*>(Cb + (size_t)row * HP + tcp) = o;
        }
    }
}

// ---------------- gather + self + bias + layernorm + relu (bf16 rows) ----------------
__global__ __launch_bounds__(256) void k_gather(const unsigned* __restrict__ Cb,
                                                const int* __restrict__ rbase,
                                                const int* __restrict__ rend,
                                                const int* __restrict__ esrc,
                                                const float* __restrict__ dinv,
                                                const float* __restrict__ b,
                                                const float* __restrict__ g,
                                                const float* __restrict__ be,
                                                unsigned* __restrict__ Ab) {
    const int lane = threadIdx.x & 63;
    int wid = (blockIdx.x * blockDim.x + threadIdx.x) >> 6;
    const int nw = (gridDim.x * blockDim.x) >> 6;
    float2 bb = reinterpret_cast<const float2*>(b)[lane];
    float2 gg = reinterpret_cast<const float2*>(g)[lane];
    float2 bee = reinterpret_cast<const float2*>(be)[lane];
    for (int i = wid; i < N_NODES; i += nw) {
        int r0 = rbase[i], r1 = rend[i];
        float ax = 0.f, ay = 0.f;
        for (int j = r0; j < r1; j += 8) {
            unsigned uu[8];
#pragma unroll
            for (int q = 0; q < 8; ++q) {
                int jq = j + q;
                unsigned u = 0;
                if (jq < r1) u = Cb[(size_t)esrc[jq] * HP + lane];
                uu[q] = u;
            }
#pragma unroll
            for (int q = 0; q < 8; ++q) {
                ax += bflo(uu[q]);
                ay += bfhi(uu[q]);
            }
        }
        unsigned us = Cb[(size_t)i * HP + lane];  // self-loop (dinv-scaled already)
        ax += bflo(us);
        ay += bfhi(us);
        float di = dinv[i];
        float vx = ax * di + bb.x;
        float vy = ay * di + bb.y;
        float s = vx + vy, sq = vx * vx + vy * vy;
#pragma unroll
        for (int o = 1; o < 64; o <<= 1) {
            s += __shfl_xor(s, o);
            sq += __shfl_xor(sq, o);
        }
        float m = s * (1.0f / HDIM);
        float var = sq * (1.0f / HDIM) - m * m;
        float rs = rsqrtf(var + 1e-5f);
        float ox = fmaxf((vx - m) * rs * gg.x + bee.x, 0.f);
        float oy = fmaxf((vy - m) * rs * gg.y + bee.y, 0.f);
        Ab[(size_t)i * HP + lane] = packbf(ox, oy);
    }
}

// ---------------- pool: pooled[batch[i]] += A[i] (bf16 rows, sorted batch) ----------------
__global__ __launch_bounds__(256) void k_pool(const unsigned* __restrict__ Ab,
                                              const int* __restrict__ batch,
                                              float* __restrict__ pooled) {
    const int CH = 16;
    const int lane = threadIdx.x & 63;
    int wid = (blockIdx.x * blockDim.x + threadIdx.x) >> 6;
    const int nw = (gridDim.x * blockDim.x) >> 6;
    const int nchunks = (N_NODES + CH - 1) / CH;
    for (int c = wid; c < nchunks; c += nw) {
        int i0 = c * CH;
        int i1 = min(i0 + CH, N_NODES);
        float ax = 0.f, ay = 0.f;
        int curb = batch[i0];
        for (int i = i0; i < i1; ++i) {
            int bg = batch[i];
            if (bg != curb) {
                float* p = pooled + (size_t)curb * HDIM + lane * 2;
                atomicAdd(p, ax);
                atomicAdd(p + 1, ay);
                ax = 0.f; ay = 0.f;
                curb = bg;
            }
            unsigned v = Ab[(size_t)i * HP + lane];
            ax += bflo(v);
            ay += bfhi(v);
        }
        float* p = pooled + (size_t)curb * HDIM + lane * 2;
        atomicAdd(p, ax);
        atomicAdd(p + 1, ay);
    }
}

// ---------------- head: out = pooled @ Wf + bf ----------------
__global__ __launch_bounds__(256) void k_head(const float* __restrict__ pooled,
                                              const float* __restrict__ Wf,
                                              const float* __restrict__ bf,
                                              float* __restrict__ out) {
    int idx = blockIdx.x * blockDim.x + threadIdx.x;
    if (idx >= N_GRAPHS * OUTDIM) return;
    int gI = idx / OUTDIM;
    int o = idx % OUTDIM;
    float acc = bf[o];
    const float* pr = pooled + (size_t)gI * HDIM;
#pragma unroll 8
    for (int k = 0; k < HDIM; ++k) acc += pr[k] * Wf[k * OUTDIM + o];
    out[idx] = acc;
}

extern "C" void kernel_launch(void* const* d_in, const int* in_sizes, int n_in,
                              void* d_out, int out_size, void* d_ws, size_t ws_size,
                              hipStream_t stream) {
    const float* x = (const float*)d_in[0];
    const int* ei = (const int*)d_in[1];
    const int* src = ei;
    const int* dst = ei + N_EDGES;
    const int* batch = (const int*)d_in[2];
    const float* W[3] = {(const float*)d_in[3], (const float*)d_in[7], (const float*)d_in[11]};
    const float* bb[3] = {(const float*)d_in[4], (const float*)d_in[8], (const float*)d_in[12]};
    const float* gg[3] = {(const float*)d_in[5], (const float*)d_in[9], (const float*)d_in[13]};
    const float* be[3] = {(const float*)d_in[6], (const float*)d_in[10], (const float*)d_in[14]};
    const float* Wf = (const float*)d_in[15];
    const float* bf = (const float*)d_in[16];
    float* out = (float*)d_out;

    char* ws = (char*)d_ws;
    float* dinv = (float*)ws;      ws += sizeof(float) * (N_NODES + 64);
    unsigned* Ab = (unsigned*)ws;  ws += sizeof(unsigned) * (size_t)N_NODES * HP;
    unsigned* Cb = (unsigned*)ws;  ws += sizeof(unsigned) * (size_t)N_NODES * HP;
    float* pooled = (float*)ws;    ws += sizeof(float) * N_GRAPHS * HDIM;
    int* rbase = (int*)ws;         ws += sizeof(int) * (N_NODES + 64);
    int* rend = (int*)ws;          ws += sizeof(int) * (N_NODES + 64);
    int* gcur = (int*)ws;          ws += sizeof(int) * (NBUCK + 64);
    unsigned* ebuck = (unsigned*)ws; ws += sizeof(unsigned) * (size_t)NBUCK * SLAB;
    int* esrc = (int*)ws;          ws += sizeof(int) * (size_t)NBUCK * SLAB;

    hipMemsetAsync(gcur, 0, NBUCK * sizeof(int), stream);
    k_bucket<<<(N_EDGES + EPB - 1) / EPB, 256, 0, stream>>>(src, dst, gcur, ebuck);
    k_bsort<<<NBUCK, 256, 0, stream>>>(gcur, ebuck, esrc, rbase, rend, dinv);

    const int gemm_blocks = (N_NODES + TM - 1) / TM;
    for (int l = 0; l < 3; ++l) {
        k_gemm<<<gemm_blocks, 256, 0, stream>>>(l == 0 ? nullptr : Ab,
                                                l == 0 ? x : nullptr,
                                                W[l], dinv, Cb);
        k_gather<<<25000, 256, 0, stream>>>(Cb, rbase, rend, esrc, dinv,
                                            bb[l], gg[l], be[l], Ab);
    }

    hipMemsetAsync(pooled, 0, N_GRAPHS * HDIM * sizeof(float), stream);
    k_pool<<<1563, 256, 0, stream>>>(Ab, batch, pooled);
    k_head<<<(N_GRAPHS * OUTDIM + 255) / 256, 256, 0, stream>>>(pooled, Wf, bf, out);
}

// Round 5
// 330.236 us; speedup vs baseline: 14.4637x; 1.8087x over previous
//
#include <hip/hip_runtime.h>

#define N_NODES 100000
#define N_EDGES 1600000
#define N_GRAPHS 512
#define HDIM 128
#define HP 64        // packed u32 per row (2 bf16 each)
#define OUTDIM 64
#define NBUCK 391    // buckets of 256 dst nodes
#define SLAB 6144    // max edges per bucket (mean 4092)
#define EPB 4096     // edges per k_bucket block

typedef short short8 __attribute__((ext_vector_type(8)));
typedef float f32x4 __attribute__((ext_vector_type(4)));
union FragU { uint4 u; short8 s; };

__device__ __forceinline__ float bflo(unsigned u) { return __uint_as_float(u << 16); }
__device__ __forceinline__ float bfhi(unsigned u) { return __uint_as_float(u & 0xffff0000u); }
__device__ __forceinline__ unsigned bf16r(float f) {
    unsigned u = __float_as_uint(f);
    return (u + 0x7fffu + ((u >> 16) & 1u)) >> 16;
}
__device__ __forceinline__ unsigned packbf(float a, float b) {
    return bf16r(a) | (bf16r(b) << 16);
}

// ---------------- phase A: bucket scatter with block-local reservation ----------------
__global__ __launch_bounds__(256) void k_bucket(const int* __restrict__ src,
                                                const int* __restrict__ dst,
                                                int* __restrict__ gcur,
                                                unsigned* __restrict__ ebuck) {
    __shared__ int hist[NBUCK];
    __shared__ int base[NBUCK];
    __shared__ int cur[NBUCK];
    const int t = threadIdx.x;
    const int e0 = blockIdx.x * EPB;
    for (int b = t; b < NBUCK; b += 256) hist[b] = 0;
    __syncthreads();
    for (int i = t; i < EPB; i += 256) {
        int e = e0 + i;
        if (e < N_EDGES) atomicAdd(&hist[dst[e] >> 8], 1);
    }
    __syncthreads();
    for (int b = t; b < NBUCK; b += 256) {
        base[b] = atomicAdd(&gcur[b], hist[b]);
        cur[b] = 0;
    }
    __syncthreads();
    for (int i = t; i < EPB; i += 256) {
        int e = e0 + i;
        if (e < N_EDGES) {
            int d = dst[e], s = src[e];
            int b = d >> 8;
            int p = base[b] + atomicAdd(&cur[b], 1);
            if (p < SLAB)
                ebuck[(size_t)b * SLAB + p] = ((unsigned)s << 8) | (unsigned)(d & 255);
        }
    }
}

// ---------------- phase B: per-bucket exact sort + rbase/rend/dinv ----------------
__global__ __launch_bounds__(256) void k_bsort(const int* __restrict__ gcur,
                                               const unsigned* __restrict__ ebuck,
                                               int* __restrict__ esrc,
                                               int* __restrict__ rbase,
                                               int* __restrict__ rend,
                                               float* __restrict__ dinv) {
    __shared__ unsigned stage[SLAB];   // 24 KB
    __shared__ int hist[256], offs[256], cur[256];
    __shared__ int wsum[4];
    const int t = threadIdx.x;
    const int b = blockIdx.x;
    const int cnt = min(gcur[b], SLAB);
    hist[t] = 0;
    cur[t] = 0;
    __syncthreads();
    for (int i = t; i < cnt; i += 256) {
        unsigned u = ebuck[(size_t)b * SLAB + i];
        stage[i] = u;
        atomicAdd(&hist[u & 255], 1);
    }
    __syncthreads();
    int v = hist[t];
    int lane = t & 63, wv = t >> 6;
    int incl = v;
#pragma unroll
    for (int o = 1; o < 64; o <<= 1) {
        int tmp = __shfl_up(incl, o);
        if (lane >= o) incl += tmp;
    }
    if (lane == 63) wsum[wv] = incl;
    __syncthreads();
    int woff = 0;
    for (int w = 0; w < wv; ++w) woff += wsum[w];
    int ex = incl - v + woff;
    offs[t] = ex;
    int d = b * 256 + t;
    if (d < N_NODES) {
        rbase[d] = b * SLAB + ex;
        rend[d] = b * SLAB + ex + v;
        dinv[d] = rsqrtf((float)v + 1.0f);
    }
    __syncthreads();
    for (int i = t; i < cnt; i += 256) {
        unsigned u = stage[i];
        int dl = u & 255;
        int p = atomicAdd(&cur[dl], 1);
        esrc[b * SLAB + offs[dl] + p] = (int)(u >> 8);
    }
}

// ---------------- W -> MFMA B-fragment layout (bf16 packed) ----------------
// Wfrag u32 layout per layer: [f=ct*4+ks][lane][j]: u32 idx = f*256 + lane*4 + j
// value = pack(bf(W[k0][n]), bf(W[k0+1][n])), n=ct*16+(lane&15), k0=ks*32+(lane>>4)*8+j*2
__global__ __launch_bounds__(256) void k_wprep(const float* __restrict__ W0,
                                               const float* __restrict__ W1,
                                               const float* __restrict__ W2,
                                               unsigned* __restrict__ Wfrag) {
    int gid = blockIdx.x * 256 + threadIdx.x;
    if (gid >= 3 * 8192) return;
    int l = gid >> 13;
    int rem = gid & 8191;
    int f = rem >> 8;
    int lane = (rem >> 2) & 63;
    int j = rem & 3;
    int ct = f >> 2, ks = f & 3;
    int n = ct * 16 + (lane & 15);
    int k0 = ks * 32 + (lane >> 4) * 8 + j * 2;
    const float* W = (l == 0) ? W0 : ((l == 1) ? W1 : W2);
    Wfrag[gid] = packbf(W[k0 * HDIM + n], W[(k0 + 1) * HDIM + n]);
}

// ---------------- MFMA GEMM: Cb = (X @ W) * dinv[row], bf16 out ----------------
// block = 4 waves x 16 rows = 64 rows; wave: 16 rows x 128 cols, K=128
__global__ __launch_bounds__(256, 2) void k_mgemm(const uint4* __restrict__ Xb4,
                                                  const float4* __restrict__ Xf4,
                                                  const uint4* __restrict__ Wfrag,
                                                  const float* __restrict__ dinv,
                                                  unsigned short* __restrict__ Cbh) {
    const int t = threadIdx.x;
    const int lane = t & 63;
    const int w = t >> 6;
    const int row0 = blockIdx.x * 64 + w * 16;
    const int lhi = lane >> 4;

    FragU B[8][4];
#pragma unroll
    for (int ct = 0; ct < 8; ++ct)
#pragma unroll
        for (int ks = 0; ks < 4; ++ks)
            B[ct][ks].u = Wfrag[(ct * 4 + ks) * 64 + lane];

    f32x4 acc[8];
#pragma unroll
    for (int ct = 0; ct < 8; ++ct) acc[ct] = (f32x4){0.f, 0.f, 0.f, 0.f};

    int arow = row0 + (lane & 15);
    int anode = (arow < N_NODES) ? arow : 0;
#pragma unroll
    for (int ks = 0; ks < 4; ++ks) {
        FragU a;
        if (Xf4) {
            float4 p = Xf4[(size_t)anode * 32 + ks * 8 + lhi * 2];
            float4 q = Xf4[(size_t)anode * 32 + ks * 8 + lhi * 2 + 1];
            a.u.x = packbf(p.x, p.y);
            a.u.y = packbf(p.z, p.w);
            a.u.z = packbf(q.x, q.y);
            a.u.w = packbf(q.z, q.w);
        } else {
            a.u = Xb4[(size_t)anode * 16 + ks * 4 + lhi];
        }
#pragma unroll
        for (int ct = 0; ct < 8; ++ct)
            acc[ct] = __builtin_amdgcn_mfma_f32_16x16x32_bf16(a.s, B[ct][ks].s, acc[ct], 0, 0, 0);
    }

    int rb = row0 + lhi * 4;
#pragma unroll
    for (int r = 0; r < 4; ++r) {
        int row = rb + r;
        if (row < N_NODES) {
            float dv = dinv[row];
#pragma unroll
            for (int ct = 0; ct < 8; ++ct) {
                int col = ct * 16 + (lane & 15);
                Cbh[(size_t)row * HDIM + col] = (unsigned short)bf16r(acc[ct][r] * dv);
            }
        }
    }
}

// ---------------- gather + self + bias + layernorm + relu (bf16 rows) ----------------
__global__ __launch_bounds__(256) void k_gather(const unsigned* __restrict__ Cb,
                                                const int* __restrict__ rbase,
                                                const int* __restrict__ rend,
                                                const int* __restrict__ esrc,
                                                const float* __restrict__ dinv,
                                                const float* __restrict__ b,
                                                const float* __restrict__ g,
                                                const float* __restrict__ be,
                                                unsigned* __restrict__ Ab) {
    const int lane = threadIdx.x & 63;
    int wid = (blockIdx.x * blockDim.x + threadIdx.x) >> 6;
    const int nw = (gridDim.x * blockDim.x) >> 6;
    float2 bb = reinterpret_cast<const float2*>(b)[lane];
    float2 gg = reinterpret_cast<const float2*>(g)[lane];
    float2 bee = reinterpret_cast<const float2*>(be)[lane];
    for (int i = wid; i < N_NODES; i += nw) {
        int r0 = rbase[i], r1 = rend[i];
        float ax = 0.f, ay = 0.f;
        for (int j = r0; j < r1; j += 16) {
            int ss[16];
#pragma unroll
            for (int q = 0; q < 16; ++q) ss[q] = (j + q < r1) ? esrc[j + q] : -1;
            unsigned uu[16];
#pragma unroll
            for (int q = 0; q < 16; ++q)
                uu[q] = (ss[q] >= 0) ? Cb[(size_t)ss[q] * HP + lane] : 0u;
#pragma unroll
            for (int q = 0; q < 16; ++q) {
                ax += bflo(uu[q]);
                ay += bfhi(uu[q]);
            }
        }
        unsigned us = Cb[(size_t)i * HP + lane];  // self-loop (dinv-scaled already)
        ax += bflo(us);
        ay += bfhi(us);
        float di = dinv[i];
        float vx = ax * di + bb.x;
        float vy = ay * di + bb.y;
        float s = vx + vy, sq = vx * vx + vy * vy;
#pragma unroll
        for (int o = 1; o < 64; o <<= 1) {
            s += __shfl_xor(s, o);
            sq += __shfl_xor(sq, o);
        }
        float m = s * (1.0f / HDIM);
        float var = sq * (1.0f / HDIM) - m * m;
        float rs = rsqrtf(var + 1e-5f);
        float ox = fmaxf((vx - m) * rs * gg.x + bee.x, 0.f);
        float oy = fmaxf((vy - m) * rs * gg.y + bee.y, 0.f);
        Ab[(size_t)i * HP + lane] = packbf(ox, oy);
    }
}

// ---------------- pool: pooled[batch[i]] += A[i] (bf16 rows, sorted batch) ----------------
__global__ __launch_bounds__(256) void k_pool(const unsigned* __restrict__ Ab,
                                              const int* __restrict__ batch,
                                              float* __restrict__ pooled) {
    const int CH = 16;
    const int lane = threadIdx.x & 63;
    int wid = (blockIdx.x * blockDim.x + threadIdx.x) >> 6;
    const int nw = (gridDim.x * blockDim.x) >> 6;
    const int nchunks = (N_NODES + CH - 1) / CH;
    for (int c = wid; c < nchunks; c += nw) {
        int i0 = c * CH;
        int i1 = min(i0 + CH, N_NODES);
        float ax = 0.f, ay = 0.f;
        int curb = batch[i0];
        for (int i = i0; i < i1; ++i) {
            int bg = batch[i];
            if (bg != curb) {
                float* p = pooled + (size_t)curb * HDIM + lane * 2;
                atomicAdd(p, ax);
                atomicAdd(p + 1, ay);
                ax = 0.f; ay = 0.f;
                curb = bg;
            }
            unsigned v = Ab[(size_t)i * HP + lane];
            ax += bflo(v);
            ay += bfhi(v);
        }
        float* p = pooled + (size_t)curb * HDIM + lane * 2;
        atomicAdd(p, ax);
        atomicAdd(p + 1, ay);
    }
}

// ---------------- head: out = pooled @ Wf + bf ----------------
__global__ __launch_bounds__(256) void k_head(const float* __restrict__ pooled,
                                              const float* __restrict__ Wf,
                                              const float* __restrict__ bf,
                                              float* __restrict__ out) {
    int idx = blockIdx.x * blockDim.x + threadIdx.x;
    if (idx >= N_GRAPHS * OUTDIM) return;
    int gI = idx / OUTDIM;
    int o = idx % OUTDIM;
    float acc = bf[o];
    const float* pr = pooled + (size_t)gI * HDIM;
#pragma unroll 8
    for (int k = 0; k < HDIM; ++k) acc += pr[k] * Wf[k * OUTDIM + o];
    out[idx] = acc;
}

extern "C" void kernel_launch(void* const* d_in, const int* in_sizes, int n_in,
                              void* d_out, int out_size, void* d_ws, size_t ws_size,
                              hipStream_t stream) {
    const float* x = (const float*)d_in[0];
    const int* ei = (const int*)d_in[1];
    const int* src = ei;
    const int* dst = ei + N_EDGES;
    const int* batch = (const int*)d_in[2];
    const float* W[3] = {(const float*)d_in[3], (const float*)d_in[7], (const float*)d_in[11]};
    const float* bb[3] = {(const float*)d_in[4], (const float*)d_in[8], (const float*)d_in[12]};
    const float* gg[3] = {(const float*)d_in[5], (const float*)d_in[9], (const float*)d_in[13]};
    const float* be[3] = {(const float*)d_in[6], (const float*)d_in[10], (const float*)d_in[14]};
    const float* Wf = (const float*)d_in[15];
    const float* bf = (const float*)d_in[16];
    float* out = (float*)d_out;

    char* ws = (char*)d_ws;
    float* dinv = (float*)ws;        ws += sizeof(float) * (N_NODES + 64);   // 16B-mult
    unsigned* Ab = (unsigned*)ws;    ws += sizeof(unsigned) * (size_t)N_NODES * HP;
    unsigned* Cb = (unsigned*)ws;    ws += sizeof(unsigned) * (size_t)N_NODES * HP;
    unsigned* Wfrag = (unsigned*)ws; ws += sizeof(unsigned) * 3 * 8192;
    float* pooled = (float*)ws;      ws += sizeof(float) * N_GRAPHS * HDIM;
    int* rbase = (int*)ws;           ws += sizeof(int) * (N_NODES + 64);
    int* rend = (int*)ws;            ws += sizeof(int) * (N_NODES + 64);
    int* gcur = (int*)ws;            ws += sizeof(int) * (NBUCK + 64);
    unsigned* ebuck = (unsigned*)ws; ws += sizeof(unsigned) * (size_t)NBUCK * SLAB;
    int* esrc = (int*)ws;            ws += sizeof(int) * (size_t)NBUCK * SLAB;

    hipMemsetAsync(gcur, 0, NBUCK * sizeof(int), stream);
    k_bucket<<<(N_EDGES + EPB - 1) / EPB, 256, 0, stream>>>(src, dst, gcur, ebuck);
    k_bsort<<<NBUCK, 256, 0, stream>>>(gcur, ebuck, esrc, rbase, rend, dinv);
    k_wprep<<<96, 256, 0, stream>>>(W[0], W[1], W[2], Wfrag);

    const int gemm_blocks = (N_NODES + 63) / 64;
    for (int l = 0; l < 3; ++l) {
        k_mgemm<<<gemm_blocks, 256, 0, stream>>>(
            l == 0 ? nullptr : (const uint4*)Ab,
            l == 0 ? (const float4*)x : nullptr,
            (const uint4*)(Wfrag + l * 8192), dinv, (unsigned short*)Cb);
        k_gather<<<25000, 256, 0, stream>>>(Cb, rbase, rend, esrc, dinv,
                                            bb[l], gg[l], be[l], Ab);
    }

    hipMemsetAsync(pooled, 0, N_GRAPHS * HDIM * sizeof(float), stream);
    k_pool<<<1563, 256, 0, stream>>>(Ab, batch, pooled);
    k_head<<<(N_GRAPHS * OUTDIM + 255) / 256, 256, 0, stream>>>(pooled, Wf, bf, out);
}